// Round 1
// baseline (1198.259 us; speedup 1.0000x reference)
//
#include <hip/hip_runtime.h>

// ---------------------------------------------------------------------------
// meta_model: out = (w0*sig(Ll Ll^T) + w1*sig((La La^T)*aa) + w2*sig((Lm Lm^T)*mod)
//                    - sig(Lu Lu^T)) * adj + sig(Lu Lu^T)
// with L* = mlp(feat), w = softmax(ws)
//
// Pipeline:
//   k_featfrag : feat f32 -> bf16, MFMA-fragment-major layout        (ws)
//   k_wfrag    : W1/W2 f32 -> bf16 fragment-major B-operand layout   (ws)
//   k_gemm1    : H = relu(feat@W1cat + b1)  -> fragment-major bf16   (ws)
//   k_gemm2    : lat = H@W2 + b2            -> fragment-major bf16   (ws)
//   k_ctx      : per 128x128 tile: 4 Grams via MFMA (K=128), fused
//                sigmoid/weighting/elementwise, streams adj/aa/mod once.
//
// Fragment-major layout for a [rows][K] bf16 matrix:
//   frag[mb][kk][lane][j]  = M[16*mb + (lane&15)][32*kk + 8*(lane>>4) + j]
// so a wave's A-frag (and, for Gram, B-frag) load is one coalesced 1KB
// global_load_dwordx4.
// ---------------------------------------------------------------------------

typedef __attribute__((ext_vector_type(8))) short short8;
typedef __attribute__((ext_vector_type(4))) float f32x4;

__device__ __forceinline__ unsigned short f2bf(float x) {
  union { float f; unsigned u; } v; v.f = x;
  unsigned u = v.u + 0x7FFFu + ((v.u >> 16) & 1u);   // round-to-nearest-even
  return (unsigned short)(u >> 16);
}

__device__ __forceinline__ float sigf(float x) {
  // sigmoid(x) = 1/(1+exp(-x)); exp(-x) = exp2(-x*log2(e))
  float e = __builtin_amdgcn_exp2f(-1.4426950408889634f * x);
  return __builtin_amdgcn_rcpf(1.0f + e);
}

// --------------------------- stage A0: feat -> frag -------------------------
__global__ __launch_bounds__(256) void k_featfrag(const float* __restrict__ feat,
                                                  unsigned short* __restrict__ dst) {
  int t = blockIdx.x * 256 + threadIdx.x;   // 8192 rows * 64 chunks
  int row = t >> 6, kc = t & 63;            // 8 cols per thread
  const float4* s = reinterpret_cast<const float4*>(feat + row * 512 + kc * 8);
  float4 v0 = s[0], v1 = s[1];
  short8 o;
  o[0] = f2bf(v0.x); o[1] = f2bf(v0.y); o[2] = f2bf(v0.z); o[3] = f2bf(v0.w);
  o[4] = f2bf(v1.x); o[5] = f2bf(v1.y); o[6] = f2bf(v1.z); o[7] = f2bf(v1.w);
  int mb = row >> 4, kk = kc >> 2;
  int lane = ((kc & 3) << 4) | (row & 15);
  *reinterpret_cast<short8*>(dst + ((size_t)((mb * 16 + kk) * 64 + lane)) * 8) = o;
}

// --------------------- stage A0w: W1/W2 -> B-frag layout ---------------------
// B-frag for C=A@B: lane l=16q+r, elem j holds B[32*kk + 8*q + j][16*nb + r]
__global__ __launch_bounds__(256) void k_wfrag(
    const float* __restrict__ w1_0, const float* __restrict__ w1_1,
    const float* __restrict__ w1_2, const float* __restrict__ w1_3,
    const float* __restrict__ w2_0, const float* __restrict__ w2_1,
    const float* __restrict__ w2_2, const float* __restrict__ w2_3,
    unsigned short* __restrict__ w1f, unsigned short* __restrict__ w2f) {
  int t = blockIdx.x * 256 + threadIdx.x;
  if (t < 32768) {  // W1frag: [g][kk=16][nb=8][lane=64][j=8]
    int lane = t & 63, nb = (t >> 6) & 7, kk = (t >> 9) & 15, g = t >> 13;
    const float* W = g == 0 ? w1_0 : g == 1 ? w1_1 : g == 2 ? w1_2 : w1_3;
    int q = lane >> 4, r = lane & 15;
    int col = nb * 16 + r;
    short8 o;
#pragma unroll
    for (int j = 0; j < 8; ++j) o[j] = f2bf(W[(kk * 32 + q * 8 + j) * 128 + col]);
    *reinterpret_cast<short8*>(w1f + (size_t)t * 8) = o;
  } else if (t < 40960) {  // W2frag: [g][kk=4][nb=8][lane=64][j=8]
    int t2 = t - 32768;
    int lane = t2 & 63, nb = (t2 >> 6) & 7, kk = (t2 >> 9) & 3, g = t2 >> 11;
    const float* W = g == 0 ? w2_0 : g == 1 ? w2_1 : g == 2 ? w2_2 : w2_3;
    int q = lane >> 4, r = lane & 15;
    int col = nb * 16 + r;
    short8 o;
#pragma unroll
    for (int j = 0; j < 8; ++j) o[j] = f2bf(W[(kk * 32 + q * 8 + j) * 128 + col]);
    *reinterpret_cast<short8*>(w2f + (size_t)t2 * 8) = o;
  }
}

// --------------------- stage A1: H = relu(feat@W1cat + b1) -------------------
// M=8192 K=512 N=512(cat of 4x128). block: 128x128 tile, 4 waves of 64x64.
__global__ __launch_bounds__(256) void k_gemm1(
    const unsigned short* __restrict__ featf, const unsigned short* __restrict__ w1f,
    const float* __restrict__ b1_0, const float* __restrict__ b1_1,
    const float* __restrict__ b1_2, const float* __restrict__ b1_3,
    unsigned short* __restrict__ hfrag) {
  int bi = blockIdx.x, g = blockIdx.y;
  int lane = threadIdx.x & 63, w = threadIdx.x >> 6;
  int wm = w >> 1, wn = w & 1;
  int q = lane >> 4, r = lane & 15;
  int mbase = 8 * bi + 4 * wm;

  f32x4 s[4][4];
#pragma unroll
  for (int mi = 0; mi < 4; ++mi)
#pragma unroll
    for (int nj = 0; nj < 4; ++nj) s[mi][nj] = (f32x4){0.f, 0.f, 0.f, 0.f};

  for (int kk = 0; kk < 16; ++kk) {
    short8 a[4], b[4];
#pragma unroll
    for (int mi = 0; mi < 4; ++mi)
      a[mi] = *reinterpret_cast<const short8*>(
          featf + ((size_t)(((mbase + mi) * 16 + kk) * 64 + lane)) * 8);
#pragma unroll
    for (int nj = 0; nj < 4; ++nj)
      b[nj] = *reinterpret_cast<const short8*>(
          w1f + ((size_t)(((g * 16 + kk) * 8 + 4 * wn + nj) * 64 + lane)) * 8);
#pragma unroll
    for (int mi = 0; mi < 4; ++mi)
#pragma unroll
      for (int nj = 0; nj < 4; ++nj)
        s[mi][nj] = __builtin_amdgcn_mfma_f32_16x16x32_bf16(a[mi], b[nj], s[mi][nj], 0, 0, 0);
  }

  const float* b1 = g == 0 ? b1_0 : g == 1 ? b1_1 : g == 2 ? b1_2 : b1_3;
#pragma unroll
  for (int nj = 0; nj < 4; ++nj) {
    int cl = 64 * wn + 16 * nj + r;        // col within this g's 128-segment
    float bias = b1[cl];
    int Cg = 128 * g + cl;                 // global H column (0..511)
    int kkd = Cg >> 5;
    int lane2hi = ((Cg >> 3) & 3) << 4;
    int j2 = Cg & 7;
#pragma unroll
    for (int mi = 0; mi < 4; ++mi) {
#pragma unroll
      for (int v = 0; v < 4; ++v) {
        int R = 128 * bi + 64 * wm + 16 * mi + 4 * q + v;
        float val = fmaxf(s[mi][nj][v] + bias, 0.0f);
        int mb = R >> 4;
        int lane2 = lane2hi | (R & 15);
        hfrag[((size_t)((mb * 16 + kkd) * 64 + lane2)) * 8 + j2] = f2bf(val);
      }
    }
  }
}

// --------------------- stage A2: lat_g = H_g@W2_g + b2 -----------------------
// per g: M=8192 K=128 N=128. block: 128 rows x 128 cols, 4 waves of 64x64.
__global__ __launch_bounds__(256) void k_gemm2(
    const unsigned short* __restrict__ hfrag, const unsigned short* __restrict__ w2f,
    const float* __restrict__ b2_0, const float* __restrict__ b2_1,
    const float* __restrict__ b2_2, const float* __restrict__ b2_3,
    unsigned short* __restrict__ latf) {
  int bi = blockIdx.x, g = blockIdx.y;
  int lane = threadIdx.x & 63, w = threadIdx.x >> 6;
  int wm = w >> 1, wn = w & 1;
  int q = lane >> 4, r = lane & 15;
  int mbase = 8 * bi + 4 * wm;

  f32x4 s[4][4];
#pragma unroll
  for (int mi = 0; mi < 4; ++mi)
#pragma unroll
    for (int nj = 0; nj < 4; ++nj) s[mi][nj] = (f32x4){0.f, 0.f, 0.f, 0.f};

#pragma unroll
  for (int kk = 0; kk < 4; ++kk) {
    short8 a[4], b[4];
#pragma unroll
    for (int mi = 0; mi < 4; ++mi)
      a[mi] = *reinterpret_cast<const short8*>(
          hfrag + ((size_t)(((mbase + mi) * 16 + 4 * g + kk) * 64 + lane)) * 8);
#pragma unroll
    for (int nj = 0; nj < 4; ++nj)
      b[nj] = *reinterpret_cast<const short8*>(
          w2f + ((size_t)(((g * 4 + kk) * 8 + 4 * wn + nj) * 64 + lane)) * 8);
#pragma unroll
    for (int mi = 0; mi < 4; ++mi)
#pragma unroll
      for (int nj = 0; nj < 4; ++nj)
        s[mi][nj] = __builtin_amdgcn_mfma_f32_16x16x32_bf16(a[mi], b[nj], s[mi][nj], 0, 0, 0);
  }

  const float* b2 = g == 0 ? b2_0 : g == 1 ? b2_1 : g == 2 ? b2_2 : b2_3;
#pragma unroll
  for (int nj = 0; nj < 4; ++nj) {
    int cl = 64 * wn + 16 * nj + r;        // lat column (0..127)
    float bias = b2[cl];
    int kkd = cl >> 5;
    int lane2hi = ((cl >> 3) & 3) << 4;
    int j2 = cl & 7;
#pragma unroll
    for (int mi = 0; mi < 4; ++mi) {
#pragma unroll
      for (int v = 0; v < 4; ++v) {
        int R = 128 * bi + 64 * wm + 16 * mi + 4 * q + v;
        float val = s[mi][nj][v] + bias;
        int mb = R >> 4;
        int lane2 = lane2hi | (R & 15);
        latf[((size_t)(((g * 512 + mb) * 4 + kkd) * 64 + lane2)) * 8 + j2] = f2bf(val);
      }
    }
  }
}

// --------------------------- stage B: fused context --------------------------
__device__ __forceinline__ void gram_tile(const unsigned short* __restrict__ latg,
                                          int mb_i, int mb_j, int lane,
                                          f32x4 s[4][4]) {
#pragma unroll
  for (int mi = 0; mi < 4; ++mi)
#pragma unroll
    for (int nj = 0; nj < 4; ++nj) s[mi][nj] = (f32x4){0.f, 0.f, 0.f, 0.f};
#pragma unroll
  for (int kk = 0; kk < 4; ++kk) {
    short8 a[4], b[4];
#pragma unroll
    for (int mi = 0; mi < 4; ++mi)
      a[mi] = *reinterpret_cast<const short8*>(
          latg + ((size_t)(((mb_i + mi) * 4 + kk) * 64 + lane)) * 8);
#pragma unroll
    for (int nj = 0; nj < 4; ++nj)
      b[nj] = *reinterpret_cast<const short8*>(
          latg + ((size_t)(((mb_j + nj) * 4 + kk) * 64 + lane)) * 8);
#pragma unroll
    for (int mi = 0; mi < 4; ++mi)
#pragma unroll
      for (int nj = 0; nj < 4; ++nj)
        s[mi][nj] = __builtin_amdgcn_mfma_f32_16x16x32_bf16(a[mi], b[nj], s[mi][nj], 0, 0, 0);
  }
}

__global__ __launch_bounds__(256) void k_ctx(
    const unsigned short* __restrict__ latf,
    const float* __restrict__ adj, const float* __restrict__ aa,
    const float* __restrict__ mod, const float* __restrict__ wsv,
    float* __restrict__ out) {
  int bj = blockIdx.x, bi = blockIdx.y;
  int lane = threadIdx.x & 63, w = threadIdx.x >> 6;
  int wm = w >> 1, wn = w & 1;
  int q = lane >> 4, r = lane & 15;

  // softmax(ws) — 3 scalars
  float s0 = wsv[0], s1 = wsv[1], s2 = wsv[2];
  float mx = fmaxf(fmaxf(s0, s1), s2);
  float e0 = __builtin_amdgcn_exp2f(1.4426950408889634f * (s0 - mx));
  float e1 = __builtin_amdgcn_exp2f(1.4426950408889634f * (s1 - mx));
  float e2 = __builtin_amdgcn_exp2f(1.4426950408889634f * (s2 - mx));
  float inv = __builtin_amdgcn_rcpf(e0 + e1 + e2);
  float w0 = e0 * inv, w1 = e1 * inv, w2 = e2 * inv;

  int mb_i = 8 * bi + 4 * wm;
  int mb_j = 8 * bj + 4 * wn;
  size_t base = (size_t)(128 * bi + 64 * wm + 4 * q) * 8192 + (size_t)(128 * bj + 64 * wn + r);
  const float* padj = adj + base;
  const float* paa  = aa + base;
  const float* pmod = mod + base;
  float* pout = out + base;

  const size_t GSTRIDE = 512u * 4u * 64u * 8u;  // elements per latent in latf

  f32x4 s[4][4], o[4][4];

  // g=0: link
  gram_tile(latf + 0 * GSTRIDE, mb_i, mb_j, lane, s);
#pragma unroll
  for (int mi = 0; mi < 4; ++mi)
#pragma unroll
    for (int nj = 0; nj < 4; ++nj)
#pragma unroll
      for (int v = 0; v < 4; ++v)
        o[mi][nj][v] = w0 * sigf(s[mi][nj][v]);

  // g=1: aa
  gram_tile(latf + 1 * GSTRIDE, mb_i, mb_j, lane, s);
#pragma unroll
  for (int mi = 0; mi < 4; ++mi)
#pragma unroll
    for (int nj = 0; nj < 4; ++nj)
#pragma unroll
      for (int v = 0; v < 4; ++v) {
        float m = paa[(size_t)(16 * mi + v) * 8192 + 16 * nj];
        o[mi][nj][v] += w1 * sigf(s[mi][nj][v] * m);
      }

  // g=2: mod
  gram_tile(latf + 2 * GSTRIDE, mb_i, mb_j, lane, s);
#pragma unroll
  for (int mi = 0; mi < 4; ++mi)
#pragma unroll
    for (int nj = 0; nj < 4; ++nj)
#pragma unroll
      for (int v = 0; v < 4; ++v) {
        float m = pmod[(size_t)(16 * mi + v) * 8192 + 16 * nj];
        o[mi][nj][v] += w2 * sigf(s[mi][nj][v] * m);
      }

  // g=3: unlink + combine + store
  gram_tile(latf + 3 * GSTRIDE, mb_i, mb_j, lane, s);
#pragma unroll
  for (int mi = 0; mi < 4; ++mi)
#pragma unroll
    for (int nj = 0; nj < 4; ++nj)
#pragma unroll
      for (int v = 0; v < 4; ++v) {
        float u = sigf(s[mi][nj][v]);
        size_t off = (size_t)(16 * mi + v) * 8192 + 16 * nj;
        float av = padj[off];
        pout[off] = av * (o[mi][nj][v] - u) + u;
      }
}

// ------------------------------------------------------------------------------
extern "C" void kernel_launch(void* const* d_in, const int* in_sizes, int n_in,
                              void* d_out, int out_size, void* d_ws, size_t ws_size,
                              hipStream_t stream) {
  const float* feat = (const float*)d_in[0];
  const float* adj  = (const float*)d_in[1];
  const float* aa   = (const float*)d_in[2];
  const float* mod  = (const float*)d_in[3];
  // g order: 0=link, 1=aa, 2=mod, 3=unlink
  const float* W1g[4] = {(const float*)d_in[4], (const float*)d_in[12],
                         (const float*)d_in[16], (const float*)d_in[8]};
  const float* b1g[4] = {(const float*)d_in[5], (const float*)d_in[13],
                         (const float*)d_in[17], (const float*)d_in[9]};
  const float* W2g[4] = {(const float*)d_in[6], (const float*)d_in[14],
                         (const float*)d_in[18], (const float*)d_in[10]};
  const float* b2g[4] = {(const float*)d_in[7], (const float*)d_in[15],
                         (const float*)d_in[19], (const float*)d_in[11]};
  const float* wsv = (const float*)d_in[20];
  float* out = (float*)d_out;

  // workspace layout (elements of ushort)
  unsigned short* featf = (unsigned short*)d_ws;   // 4,194,304 elems (8 MiB)
  unsigned short* hfrag = featf + 4194304;         // 4,194,304
  unsigned short* latf  = hfrag + 4194304;         // 4,194,304
  unsigned short* w1f   = latf + 4194304;          //   262,144
  unsigned short* w2f   = w1f + 262144;            //    65,536
  // total 25,821,184 bytes
  if (ws_size < 25821184) return;

  k_featfrag<<<2048, 256, 0, stream>>>(feat, featf);
  k_wfrag<<<160, 256, 0, stream>>>(W1g[0], W1g[1], W1g[2], W1g[3],
                                   W2g[0], W2g[1], W2g[2], W2g[3], w1f, w2f);
  k_gemm1<<<dim3(64, 4), 256, 0, stream>>>(featf, w1f, b1g[0], b1g[1], b1g[2], b1g[3], hfrag);
  k_gemm2<<<dim3(64, 4), 256, 0, stream>>>(hfrag, w2f, b2g[0], b2g[1], b2g[2], b2g[3], latf);
  k_ctx<<<dim3(64, 64), 256, 0, stream>>>(latf, adj, aa, mod, wsv, out);
}

// Round 2
// 567.667 us; speedup vs baseline: 2.1108x; 2.1108x over previous
//
#include <hip/hip_runtime.h>

// ---------------------------------------------------------------------------
// meta_model: out = (w0*sig(Ll Ll^T) + w1*sig((La La^T)*aa) + w2*sig((Lm Lm^T)*mod)
//                    - sig(Lu Lu^T)) * adj + sig(Lu Lu^T)
// with L* = mlp(feat), w = softmax(ws)
//
// Pipeline:
//   k_featfrag : feat f32 -> bf16, MFMA-fragment-major layout        (ws)
//   k_wfrag    : W1/W2 f32 -> bf16 fragment-major B-operand layout   (ws)
//   k_gemm1    : H = relu(feat@W1cat + b1)  -> fragment-major bf16   (ws)
//   k_gemm2    : lat = H@W2 + b2            -> fragment-major bf16   (ws)
//   k_ctx      : per 128x64 tile: 4 Grams via MFMA (K=128), fused
//                sigmoid/weighting/elementwise, streams adj/aa/mod once.
//
// R1 changes vs R0 (k_ctx was latency-bound, 136 VGPR all eaten by 128
// accumulators -> no memory-level parallelism):
//   - wave tile 64x64 -> 64x32 (s[4][2]+o[4][2] = 64 accum regs)
//   - swapped MFMA operands in the Gram: mfma(frag_j, frag_i) = Lj*Li^T,
//     so each lane's 4-reg quad spans 4 CONSECUTIVE output columns ->
//     float4 loads/stores for adj/aa/mod/out
//   - __launch_bounds__(256,4): cap 128 VGPR -> 16 waves/CU
//   - XCD-aware bijective block swizzle (8192 blocks % 8 == 0)
// ---------------------------------------------------------------------------

typedef __attribute__((ext_vector_type(8))) short short8;
typedef __attribute__((ext_vector_type(4))) float f32x4;

__device__ __forceinline__ unsigned short f2bf(float x) {
  union { float f; unsigned u; } v; v.f = x;
  unsigned u = v.u + 0x7FFFu + ((v.u >> 16) & 1u);   // round-to-nearest-even
  return (unsigned short)(u >> 16);
}

__device__ __forceinline__ float sigf(float x) {
  float e = __builtin_amdgcn_exp2f(-1.4426950408889634f * x);
  return __builtin_amdgcn_rcpf(1.0f + e);
}

// --------------------------- stage A0: feat -> frag -------------------------
__global__ __launch_bounds__(256) void k_featfrag(const float* __restrict__ feat,
                                                  unsigned short* __restrict__ dst) {
  int t = blockIdx.x * 256 + threadIdx.x;   // 8192 rows * 64 chunks
  int row = t >> 6, kc = t & 63;            // 8 cols per thread
  const float4* s = reinterpret_cast<const float4*>(feat + row * 512 + kc * 8);
  float4 v0 = s[0], v1 = s[1];
  short8 o;
  o[0] = f2bf(v0.x); o[1] = f2bf(v0.y); o[2] = f2bf(v0.z); o[3] = f2bf(v0.w);
  o[4] = f2bf(v1.x); o[5] = f2bf(v1.y); o[6] = f2bf(v1.z); o[7] = f2bf(v1.w);
  int mb = row >> 4, kk = kc >> 2;
  int lane = ((kc & 3) << 4) | (row & 15);
  *reinterpret_cast<short8*>(dst + ((size_t)((mb * 16 + kk) * 64 + lane)) * 8) = o;
}

// --------------------- stage A0w: W1/W2 -> B-frag layout ---------------------
__global__ __launch_bounds__(256) void k_wfrag(
    const float* __restrict__ w1_0, const float* __restrict__ w1_1,
    const float* __restrict__ w1_2, const float* __restrict__ w1_3,
    const float* __restrict__ w2_0, const float* __restrict__ w2_1,
    const float* __restrict__ w2_2, const float* __restrict__ w2_3,
    unsigned short* __restrict__ w1f, unsigned short* __restrict__ w2f) {
  int t = blockIdx.x * 256 + threadIdx.x;
  if (t < 32768) {  // W1frag: [g][kk=16][nb=8][lane=64][j=8]
    int lane = t & 63, nb = (t >> 6) & 7, kk = (t >> 9) & 15, g = t >> 13;
    const float* W = g == 0 ? w1_0 : g == 1 ? w1_1 : g == 2 ? w1_2 : w1_3;
    int q = lane >> 4, r = lane & 15;
    int col = nb * 16 + r;
    short8 o;
#pragma unroll
    for (int j = 0; j < 8; ++j) o[j] = f2bf(W[(kk * 32 + q * 8 + j) * 128 + col]);
    *reinterpret_cast<short8*>(w1f + (size_t)t * 8) = o;
  } else if (t < 40960) {  // W2frag: [g][kk=4][nb=8][lane=64][j=8]
    int t2 = t - 32768;
    int lane = t2 & 63, nb = (t2 >> 6) & 7, kk = (t2 >> 9) & 3, g = t2 >> 11;
    const float* W = g == 0 ? w2_0 : g == 1 ? w2_1 : g == 2 ? w2_2 : w2_3;
    int q = lane >> 4, r = lane & 15;
    int col = nb * 16 + r;
    short8 o;
#pragma unroll
    for (int j = 0; j < 8; ++j) o[j] = f2bf(W[(kk * 32 + q * 8 + j) * 128 + col]);
    *reinterpret_cast<short8*>(w2f + (size_t)t2 * 8) = o;
  }
}

// --------------------- stage A1: H = relu(feat@W1cat + b1) -------------------
__global__ __launch_bounds__(256) void k_gemm1(
    const unsigned short* __restrict__ featf, const unsigned short* __restrict__ w1f,
    const float* __restrict__ b1_0, const float* __restrict__ b1_1,
    const float* __restrict__ b1_2, const float* __restrict__ b1_3,
    unsigned short* __restrict__ hfrag) {
  int bi = blockIdx.x, g = blockIdx.y;
  int lane = threadIdx.x & 63, w = threadIdx.x >> 6;
  int wm = w >> 1, wn = w & 1;
  int q = lane >> 4, r = lane & 15;
  int mbase = 8 * bi + 4 * wm;

  f32x4 s[4][4];
#pragma unroll
  for (int mi = 0; mi < 4; ++mi)
#pragma unroll
    for (int nj = 0; nj < 4; ++nj) s[mi][nj] = (f32x4){0.f, 0.f, 0.f, 0.f};

  for (int kk = 0; kk < 16; ++kk) {
    short8 a[4], b[4];
#pragma unroll
    for (int mi = 0; mi < 4; ++mi)
      a[mi] = *reinterpret_cast<const short8*>(
          featf + ((size_t)(((mbase + mi) * 16 + kk) * 64 + lane)) * 8);
#pragma unroll
    for (int nj = 0; nj < 4; ++nj)
      b[nj] = *reinterpret_cast<const short8*>(
          w1f + ((size_t)(((g * 16 + kk) * 8 + 4 * wn + nj) * 64 + lane)) * 8);
#pragma unroll
    for (int mi = 0; mi < 4; ++mi)
#pragma unroll
      for (int nj = 0; nj < 4; ++nj)
        s[mi][nj] = __builtin_amdgcn_mfma_f32_16x16x32_bf16(a[mi], b[nj], s[mi][nj], 0, 0, 0);
  }

  const float* b1 = g == 0 ? b1_0 : g == 1 ? b1_1 : g == 2 ? b1_2 : b1_3;
#pragma unroll
  for (int nj = 0; nj < 4; ++nj) {
    int cl = 64 * wn + 16 * nj + r;
    float bias = b1[cl];
    int Cg = 128 * g + cl;
    int kkd = Cg >> 5;
    int lane2hi = ((Cg >> 3) & 3) << 4;
    int j2 = Cg & 7;
#pragma unroll
    for (int mi = 0; mi < 4; ++mi) {
#pragma unroll
      for (int v = 0; v < 4; ++v) {
        int R = 128 * bi + 64 * wm + 16 * mi + 4 * q + v;
        float val = fmaxf(s[mi][nj][v] + bias, 0.0f);
        int mb = R >> 4;
        int lane2 = lane2hi | (R & 15);
        hfrag[((size_t)((mb * 16 + kkd) * 64 + lane2)) * 8 + j2] = f2bf(val);
      }
    }
  }
}

// --------------------- stage A2: lat_g = H_g@W2_g + b2 -----------------------
__global__ __launch_bounds__(256) void k_gemm2(
    const unsigned short* __restrict__ hfrag, const unsigned short* __restrict__ w2f,
    const float* __restrict__ b2_0, const float* __restrict__ b2_1,
    const float* __restrict__ b2_2, const float* __restrict__ b2_3,
    unsigned short* __restrict__ latf) {
  int bi = blockIdx.x, g = blockIdx.y;
  int lane = threadIdx.x & 63, w = threadIdx.x >> 6;
  int wm = w >> 1, wn = w & 1;
  int q = lane >> 4, r = lane & 15;
  int mbase = 8 * bi + 4 * wm;

  f32x4 s[4][4];
#pragma unroll
  for (int mi = 0; mi < 4; ++mi)
#pragma unroll
    for (int nj = 0; nj < 4; ++nj) s[mi][nj] = (f32x4){0.f, 0.f, 0.f, 0.f};

#pragma unroll
  for (int kk = 0; kk < 4; ++kk) {
    short8 a[4], b[4];
#pragma unroll
    for (int mi = 0; mi < 4; ++mi)
      a[mi] = *reinterpret_cast<const short8*>(
          hfrag + ((size_t)(((mbase + mi) * 16 + 4 * g + kk) * 64 + lane)) * 8);
#pragma unroll
    for (int nj = 0; nj < 4; ++nj)
      b[nj] = *reinterpret_cast<const short8*>(
          w2f + ((size_t)(((g * 4 + kk) * 8 + 4 * wn + nj) * 64 + lane)) * 8);
#pragma unroll
    for (int mi = 0; mi < 4; ++mi)
#pragma unroll
      for (int nj = 0; nj < 4; ++nj)
        s[mi][nj] = __builtin_amdgcn_mfma_f32_16x16x32_bf16(a[mi], b[nj], s[mi][nj], 0, 0, 0);
  }

  const float* b2 = g == 0 ? b2_0 : g == 1 ? b2_1 : g == 2 ? b2_2 : b2_3;
#pragma unroll
  for (int nj = 0; nj < 4; ++nj) {
    int cl = 64 * wn + 16 * nj + r;
    float bias = b2[cl];
    int kkd = cl >> 5;
    int lane2hi = ((cl >> 3) & 3) << 4;
    int j2 = cl & 7;
#pragma unroll
    for (int mi = 0; mi < 4; ++mi) {
#pragma unroll
      for (int v = 0; v < 4; ++v) {
        int R = 128 * bi + 64 * wm + 16 * mi + 4 * q + v;
        float val = s[mi][nj][v] + bias;
        int mb = R >> 4;
        int lane2 = lane2hi | (R & 15);
        latf[((size_t)(((g * 512 + mb) * 4 + kkd) * 64 + lane2)) * 8 + j2] = f2bf(val);
      }
    }
  }
}

// --------------------------- stage B: fused context --------------------------
// Transposed-Gram: s[mi][nj] = sum_k mfma(frag_j, frag_i)  == Lj * Li^T tile.
// Lane l=16q+r, reg v then owns out(row = 16mi + r, col = 16nj + 4q + v):
// 4 consecutive output columns -> float4 elementwise IO.
__device__ __forceinline__ void gram_tile_T(const unsigned short* __restrict__ latg,
                                            int mb_i, int mb_j, int lane,
                                            f32x4 s[4][2]) {
#pragma unroll
  for (int mi = 0; mi < 4; ++mi)
#pragma unroll
    for (int nj = 0; nj < 2; ++nj) s[mi][nj] = (f32x4){0.f, 0.f, 0.f, 0.f};
#pragma unroll
  for (int kk = 0; kk < 4; ++kk) {
    short8 fi[4], fj[2];
#pragma unroll
    for (int mi = 0; mi < 4; ++mi)
      fi[mi] = *reinterpret_cast<const short8*>(
          latg + ((size_t)(((mb_i + mi) * 4 + kk) * 64 + lane)) * 8);
#pragma unroll
    for (int nj = 0; nj < 2; ++nj)
      fj[nj] = *reinterpret_cast<const short8*>(
          latg + ((size_t)(((mb_j + nj) * 4 + kk) * 64 + lane)) * 8);
#pragma unroll
    for (int mi = 0; mi < 4; ++mi)
#pragma unroll
      for (int nj = 0; nj < 2; ++nj)
        s[mi][nj] = __builtin_amdgcn_mfma_f32_16x16x32_bf16(fj[nj], fi[mi], s[mi][nj], 0, 0, 0);
  }
}

__global__ __launch_bounds__(256, 4) void k_ctx(
    const unsigned short* __restrict__ latf,
    const float* __restrict__ adj, const float* __restrict__ aa,
    const float* __restrict__ mod, const float* __restrict__ wsv,
    float* __restrict__ out) {
  // 8192 blocks = 64 (bi, 128-row tiles) x 128 (bj, 64-col tiles).
  // XCD-aware bijective swizzle: each XCD sweeps bj fast with 8 resident
  // bi-panels -> latf A-panels stay L2-hot.
  int bid = blockIdx.x;
  int swz = (bid & 7) * 1024 + (bid >> 3);
  int bi = swz >> 7;
  int bj = swz & 127;

  int lane = threadIdx.x & 63, w = threadIdx.x >> 6;
  int wm = w >> 1, wn = w & 1;            // 2x2 waves of 64x32
  int q = lane >> 4, r = lane & 15;

  // softmax(ws) — 3 scalars
  float s0 = wsv[0], s1 = wsv[1], s2 = wsv[2];
  float mx = fmaxf(fmaxf(s0, s1), s2);
  float e0 = __builtin_amdgcn_exp2f(1.4426950408889634f * (s0 - mx));
  float e1 = __builtin_amdgcn_exp2f(1.4426950408889634f * (s1 - mx));
  float e2 = __builtin_amdgcn_exp2f(1.4426950408889634f * (s2 - mx));
  float inv = __builtin_amdgcn_rcpf(e0 + e1 + e2);
  float w0 = e0 * inv, w1 = e1 * inv, w2 = e2 * inv;

  int mb_i = 8 * bi + 4 * wm;             // 16-row block base (rows)
  int mb_j = 4 * bj + 2 * wn;             // 16-row block base (cols)

  // elementwise base: row = 128bi + 64wm + r, col = 64bj + 32wn + 4q
  size_t ewbase = (size_t)(128 * bi + 64 * wm + r) * 8192
                + (size_t)(64 * bj + 32 * wn + 4 * q);

  const size_t GSTRIDE = 512u * 4u * 64u * 8u;  // elements per latent in latf

  f32x4 s[4][2], o[4][2];

  // g=0: link (no elementwise input)
  gram_tile_T(latf + 0 * GSTRIDE, mb_i, mb_j, lane, s);
#pragma unroll
  for (int mi = 0; mi < 4; ++mi)
#pragma unroll
    for (int nj = 0; nj < 2; ++nj)
#pragma unroll
      for (int v = 0; v < 4; ++v)
        o[mi][nj][v] = w0 * sigf(s[mi][nj][v]);

  // g=1: aa
  gram_tile_T(latf + 1 * GSTRIDE, mb_i, mb_j, lane, s);
#pragma unroll
  for (int mi = 0; mi < 4; ++mi)
#pragma unroll
    for (int nj = 0; nj < 2; ++nj) {
      f32x4 m = *reinterpret_cast<const f32x4*>(aa + ewbase + (size_t)(16 * mi) * 8192 + 16 * nj);
#pragma unroll
      for (int v = 0; v < 4; ++v)
        o[mi][nj][v] += w1 * sigf(s[mi][nj][v] * m[v]);
    }

  // g=2: mod
  gram_tile_T(latf + 2 * GSTRIDE, mb_i, mb_j, lane, s);
#pragma unroll
  for (int mi = 0; mi < 4; ++mi)
#pragma unroll
    for (int nj = 0; nj < 2; ++nj) {
      f32x4 m = *reinterpret_cast<const f32x4*>(mod + ewbase + (size_t)(16 * mi) * 8192 + 16 * nj);
#pragma unroll
      for (int v = 0; v < 4; ++v)
        o[mi][nj][v] += w2 * sigf(s[mi][nj][v] * m[v]);
    }

  // g=3: unlink + combine + store
  gram_tile_T(latf + 3 * GSTRIDE, mb_i, mb_j, lane, s);
#pragma unroll
  for (int mi = 0; mi < 4; ++mi)
#pragma unroll
    for (int nj = 0; nj < 2; ++nj) {
      size_t off = ewbase + (size_t)(16 * mi) * 8192 + 16 * nj;
      f32x4 av = *reinterpret_cast<const f32x4*>(adj + off);
      f32x4 res;
#pragma unroll
      for (int v = 0; v < 4; ++v) {
        float u = sigf(s[mi][nj][v]);
        res[v] = av[v] * (o[mi][nj][v] - u) + u;
      }
      *reinterpret_cast<f32x4*>(out + off) = res;
    }
}

// ------------------------------------------------------------------------------
extern "C" void kernel_launch(void* const* d_in, const int* in_sizes, int n_in,
                              void* d_out, int out_size, void* d_ws, size_t ws_size,
                              hipStream_t stream) {
  const float* feat = (const float*)d_in[0];
  const float* adj  = (const float*)d_in[1];
  const float* aa   = (const float*)d_in[2];
  const float* mod  = (const float*)d_in[3];
  // g order: 0=link, 1=aa, 2=mod, 3=unlink
  const float* W1g[4] = {(const float*)d_in[4], (const float*)d_in[12],
                         (const float*)d_in[16], (const float*)d_in[8]};
  const float* b1g[4] = {(const float*)d_in[5], (const float*)d_in[13],
                         (const float*)d_in[17], (const float*)d_in[9]};
  const float* W2g[4] = {(const float*)d_in[6], (const float*)d_in[14],
                         (const float*)d_in[18], (const float*)d_in[10]};
  const float* b2g[4] = {(const float*)d_in[7], (const float*)d_in[15],
                         (const float*)d_in[19], (const float*)d_in[11]};
  const float* wsv = (const float*)d_in[20];
  float* out = (float*)d_out;

  // workspace layout (elements of ushort)
  unsigned short* featf = (unsigned short*)d_ws;   // 4,194,304 elems (8 MiB)
  unsigned short* hfrag = featf + 4194304;         // 4,194,304
  unsigned short* latf  = hfrag + 4194304;         // 4,194,304
  unsigned short* w1f   = latf + 4194304;          //   262,144
  unsigned short* w2f   = w1f + 262144;            //    65,536
  if (ws_size < 25821184) return;

  k_featfrag<<<2048, 256, 0, stream>>>(feat, featf);
  k_wfrag<<<160, 256, 0, stream>>>(W1g[0], W1g[1], W1g[2], W1g[3],
                                   W2g[0], W2g[1], W2g[2], W2g[3], w1f, w2f);
  k_gemm1<<<dim3(64, 4), 256, 0, stream>>>(featf, w1f, b1g[0], b1g[1], b1g[2], b1g[3], hfrag);
  k_gemm2<<<dim3(64, 4), 256, 0, stream>>>(hfrag, w2f, b2g[0], b2g[1], b2g[2], b2g[3], latf);
  k_ctx<<<8192, 256, 0, stream>>>(latf, adj, aa, mod, wsv, out);
}

// Round 3
// 432.744 us; speedup vs baseline: 2.7690x; 1.3118x over previous
//
#include <hip/hip_runtime.h>

// ---------------------------------------------------------------------------
// meta_model: out = (w0*sig(Ll Ll^T) + w1*sig((La La^T)*aa) + w2*sig((Lm Lm^T)*mod)
//                    - sig(Lu Lu^T)) * adj + sig(Lu Lu^T)
// with L* = mlp(feat), w = softmax(ws)
//
// R2 changes vs R1 (k_ctx was STILL latency-bound: VGPR_Count=64 == exactly
// the accumulator count -> compiler had no registers for in-flight loads,
// ~10 lines outstanding/wave, 2.98 TB/s):
//   - explicit double-buffered register prefetch of aa/mod/adj tiles,
//     issued one full gram phase before consumption
//   - __launch_bounds__(256,3): VGPR cap ~168 so the prefetch batches and
//     MFMA fragments can all be in flight (s32+o32+ewA32+ewB32+frags24)
// ---------------------------------------------------------------------------

typedef __attribute__((ext_vector_type(8))) short short8;
typedef __attribute__((ext_vector_type(4))) float f32x4;

__device__ __forceinline__ unsigned short f2bf(float x) {
  union { float f; unsigned u; } v; v.f = x;
  unsigned u = v.u + 0x7FFFu + ((v.u >> 16) & 1u);   // round-to-nearest-even
  return (unsigned short)(u >> 16);
}

__device__ __forceinline__ float sigf(float x) {
  float e = __builtin_amdgcn_exp2f(-1.4426950408889634f * x);
  return __builtin_amdgcn_rcpf(1.0f + e);
}

// --------------------------- stage A0: feat -> frag -------------------------
__global__ __launch_bounds__(256) void k_featfrag(const float* __restrict__ feat,
                                                  unsigned short* __restrict__ dst) {
  int t = blockIdx.x * 256 + threadIdx.x;   // 8192 rows * 64 chunks
  int row = t >> 6, kc = t & 63;            // 8 cols per thread
  const float4* s = reinterpret_cast<const float4*>(feat + row * 512 + kc * 8);
  float4 v0 = s[0], v1 = s[1];
  short8 o;
  o[0] = f2bf(v0.x); o[1] = f2bf(v0.y); o[2] = f2bf(v0.z); o[3] = f2bf(v0.w);
  o[4] = f2bf(v1.x); o[5] = f2bf(v1.y); o[6] = f2bf(v1.z); o[7] = f2bf(v1.w);
  int mb = row >> 4, kk = kc >> 2;
  int lane = ((kc & 3) << 4) | (row & 15);
  *reinterpret_cast<short8*>(dst + ((size_t)((mb * 16 + kk) * 64 + lane)) * 8) = o;
}

// --------------------- stage A0w: W1/W2 -> B-frag layout ---------------------
__global__ __launch_bounds__(256) void k_wfrag(
    const float* __restrict__ w1_0, const float* __restrict__ w1_1,
    const float* __restrict__ w1_2, const float* __restrict__ w1_3,
    const float* __restrict__ w2_0, const float* __restrict__ w2_1,
    const float* __restrict__ w2_2, const float* __restrict__ w2_3,
    unsigned short* __restrict__ w1f, unsigned short* __restrict__ w2f) {
  int t = blockIdx.x * 256 + threadIdx.x;
  if (t < 32768) {  // W1frag: [g][kk=16][nb=8][lane=64][j=8]
    int lane = t & 63, nb = (t >> 6) & 7, kk = (t >> 9) & 15, g = t >> 13;
    const float* W = g == 0 ? w1_0 : g == 1 ? w1_1 : g == 2 ? w1_2 : w1_3;
    int q = lane >> 4, r = lane & 15;
    int col = nb * 16 + r;
    short8 o;
#pragma unroll
    for (int j = 0; j < 8; ++j) o[j] = f2bf(W[(kk * 32 + q * 8 + j) * 128 + col]);
    *reinterpret_cast<short8*>(w1f + (size_t)t * 8) = o;
  } else if (t < 40960) {  // W2frag: [g][kk=4][nb=8][lane=64][j=8]
    int t2 = t - 32768;
    int lane = t2 & 63, nb = (t2 >> 6) & 7, kk = (t2 >> 9) & 3, g = t2 >> 11;
    const float* W = g == 0 ? w2_0 : g == 1 ? w2_1 : g == 2 ? w2_2 : w2_3;
    int q = lane >> 4, r = lane & 15;
    int col = nb * 16 + r;
    short8 o;
#pragma unroll
    for (int j = 0; j < 8; ++j) o[j] = f2bf(W[(kk * 32 + q * 8 + j) * 128 + col]);
    *reinterpret_cast<short8*>(w2f + (size_t)t2 * 8) = o;
  }
}

// --------------------- stage A1: H = relu(feat@W1cat + b1) -------------------
__global__ __launch_bounds__(256) void k_gemm1(
    const unsigned short* __restrict__ featf, const unsigned short* __restrict__ w1f,
    const float* __restrict__ b1_0, const float* __restrict__ b1_1,
    const float* __restrict__ b1_2, const float* __restrict__ b1_3,
    unsigned short* __restrict__ hfrag) {
  int bi = blockIdx.x, g = blockIdx.y;
  int lane = threadIdx.x & 63, w = threadIdx.x >> 6;
  int wm = w >> 1, wn = w & 1;
  int q = lane >> 4, r = lane & 15;
  int mbase = 8 * bi + 4 * wm;

  f32x4 s[4][4];
#pragma unroll
  for (int mi = 0; mi < 4; ++mi)
#pragma unroll
    for (int nj = 0; nj < 4; ++nj) s[mi][nj] = (f32x4){0.f, 0.f, 0.f, 0.f};

  for (int kk = 0; kk < 16; ++kk) {
    short8 a[4], b[4];
#pragma unroll
    for (int mi = 0; mi < 4; ++mi)
      a[mi] = *reinterpret_cast<const short8*>(
          featf + ((size_t)(((mbase + mi) * 16 + kk) * 64 + lane)) * 8);
#pragma unroll
    for (int nj = 0; nj < 4; ++nj)
      b[nj] = *reinterpret_cast<const short8*>(
          w1f + ((size_t)(((g * 16 + kk) * 8 + 4 * wn + nj) * 64 + lane)) * 8);
#pragma unroll
    for (int mi = 0; mi < 4; ++mi)
#pragma unroll
      for (int nj = 0; nj < 4; ++nj)
        s[mi][nj] = __builtin_amdgcn_mfma_f32_16x16x32_bf16(a[mi], b[nj], s[mi][nj], 0, 0, 0);
  }

  const float* b1 = g == 0 ? b1_0 : g == 1 ? b1_1 : g == 2 ? b1_2 : b1_3;
#pragma unroll
  for (int nj = 0; nj < 4; ++nj) {
    int cl = 64 * wn + 16 * nj + r;
    float bias = b1[cl];
    int Cg = 128 * g + cl;
    int kkd = Cg >> 5;
    int lane2hi = ((Cg >> 3) & 3) << 4;
    int j2 = Cg & 7;
#pragma unroll
    for (int mi = 0; mi < 4; ++mi) {
#pragma unroll
      for (int v = 0; v < 4; ++v) {
        int R = 128 * bi + 64 * wm + 16 * mi + 4 * q + v;
        float val = fmaxf(s[mi][nj][v] + bias, 0.0f);
        int mb = R >> 4;
        int lane2 = lane2hi | (R & 15);
        hfrag[((size_t)((mb * 16 + kkd) * 64 + lane2)) * 8 + j2] = f2bf(val);
      }
    }
  }
}

// --------------------- stage A2: lat_g = H_g@W2_g + b2 -----------------------
__global__ __launch_bounds__(256) void k_gemm2(
    const unsigned short* __restrict__ hfrag, const unsigned short* __restrict__ w2f,
    const float* __restrict__ b2_0, const float* __restrict__ b2_1,
    const float* __restrict__ b2_2, const float* __restrict__ b2_3,
    unsigned short* __restrict__ latf) {
  int bi = blockIdx.x, g = blockIdx.y;
  int lane = threadIdx.x & 63, w = threadIdx.x >> 6;
  int wm = w >> 1, wn = w & 1;
  int q = lane >> 4, r = lane & 15;
  int mbase = 8 * bi + 4 * wm;

  f32x4 s[4][4];
#pragma unroll
  for (int mi = 0; mi < 4; ++mi)
#pragma unroll
    for (int nj = 0; nj < 4; ++nj) s[mi][nj] = (f32x4){0.f, 0.f, 0.f, 0.f};

#pragma unroll
  for (int kk = 0; kk < 4; ++kk) {
    short8 a[4], b[4];
#pragma unroll
    for (int mi = 0; mi < 4; ++mi)
      a[mi] = *reinterpret_cast<const short8*>(
          hfrag + ((size_t)(((mbase + mi) * 16 + 4 * g + kk) * 64 + lane)) * 8);
#pragma unroll
    for (int nj = 0; nj < 4; ++nj)
      b[nj] = *reinterpret_cast<const short8*>(
          w2f + ((size_t)(((g * 4 + kk) * 8 + 4 * wn + nj) * 64 + lane)) * 8);
#pragma unroll
    for (int mi = 0; mi < 4; ++mi)
#pragma unroll
      for (int nj = 0; nj < 4; ++nj)
        s[mi][nj] = __builtin_amdgcn_mfma_f32_16x16x32_bf16(a[mi], b[nj], s[mi][nj], 0, 0, 0);
  }

  const float* b2 = g == 0 ? b2_0 : g == 1 ? b2_1 : g == 2 ? b2_2 : b2_3;
#pragma unroll
  for (int nj = 0; nj < 4; ++nj) {
    int cl = 64 * wn + 16 * nj + r;
    float bias = b2[cl];
    int kkd = cl >> 5;
    int lane2hi = ((cl >> 3) & 3) << 4;
    int j2 = cl & 7;
#pragma unroll
    for (int mi = 0; mi < 4; ++mi) {
#pragma unroll
      for (int v = 0; v < 4; ++v) {
        int R = 128 * bi + 64 * wm + 16 * mi + 4 * q + v;
        float val = s[mi][nj][v] + bias;
        int mb = R >> 4;
        int lane2 = lane2hi | (R & 15);
        latf[((size_t)(((g * 512 + mb) * 4 + kkd) * 64 + lane2)) * 8 + j2] = f2bf(val);
      }
    }
  }
}

// --------------------------- stage B: fused context --------------------------
// Transposed-Gram: s[mi][nj] = sum_k mfma(frag_j, frag_i)  == Lj * Li^T tile.
// Lane l=16q+r, reg v then owns out(row = 16mi + r, col = 16nj + 4q + v).
__device__ __forceinline__ void gram_tile_T(const unsigned short* __restrict__ latg,
                                            int mb_i, int mb_j, int lane,
                                            f32x4 s[4][2]) {
#pragma unroll
  for (int mi = 0; mi < 4; ++mi)
#pragma unroll
    for (int nj = 0; nj < 2; ++nj) s[mi][nj] = (f32x4){0.f, 0.f, 0.f, 0.f};
#pragma unroll
  for (int kk = 0; kk < 4; ++kk) {
    short8 fi[4], fj[2];
#pragma unroll
    for (int mi = 0; mi < 4; ++mi)
      fi[mi] = *reinterpret_cast<const short8*>(
          latg + ((size_t)(((mb_i + mi) * 4 + kk) * 64 + lane)) * 8);
#pragma unroll
    for (int nj = 0; nj < 2; ++nj)
      fj[nj] = *reinterpret_cast<const short8*>(
          latg + ((size_t)(((mb_j + nj) * 4 + kk) * 64 + lane)) * 8);
#pragma unroll
    for (int mi = 0; mi < 4; ++mi)
#pragma unroll
      for (int nj = 0; nj < 2; ++nj)
        s[mi][nj] = __builtin_amdgcn_mfma_f32_16x16x32_bf16(fj[nj], fi[mi], s[mi][nj], 0, 0, 0);
  }
}

__global__ __launch_bounds__(256, 3) void k_ctx(
    const unsigned short* __restrict__ latf,
    const float* __restrict__ adj, const float* __restrict__ aa,
    const float* __restrict__ mod, const float* __restrict__ wsv,
    float* __restrict__ out) {
  // 8192 blocks = 64 (bi, 128-row tiles) x 128 (bj, 64-col tiles).
  // XCD-aware bijective swizzle: each XCD sweeps bj fast with a resident
  // bi-panel -> latf A-panels stay L2-hot.
  int bid = blockIdx.x;
  int swz = (bid & 7) * 1024 + (bid >> 3);
  int bi = swz >> 7;
  int bj = swz & 127;

  int lane = threadIdx.x & 63, w = threadIdx.x >> 6;
  int wm = w >> 1, wn = w & 1;            // 2x2 waves of 64x32
  int q = lane >> 4, r = lane & 15;

  // softmax(ws) — 3 scalars
  float s0 = wsv[0], s1 = wsv[1], s2 = wsv[2];
  float mx = fmaxf(fmaxf(s0, s1), s2);
  float e0 = __builtin_amdgcn_exp2f(1.4426950408889634f * (s0 - mx));
  float e1 = __builtin_amdgcn_exp2f(1.4426950408889634f * (s1 - mx));
  float e2 = __builtin_amdgcn_exp2f(1.4426950408889634f * (s2 - mx));
  float inv = __builtin_amdgcn_rcpf(e0 + e1 + e2);
  float w0 = e0 * inv, w1 = e1 * inv, w2 = e2 * inv;

  int mb_i = 8 * bi + 4 * wm;             // 16-row block base (rows)
  int mb_j = 4 * bj + 2 * wn;             // 16-row block base (cols)

  // elementwise base: row = 128bi + 64wm + r, col = 64bj + 32wn + 4q
  size_t ewbase = (size_t)(128 * bi + 64 * wm + r) * 8192
                + (size_t)(64 * bj + 32 * wn + 4 * q);

  const size_t GSTRIDE = 512u * 4u * 64u * 8u;  // elements per latent in latf

  f32x4 s[4][2], o[4][2];
  f32x4 ewA[4][2], ewB[4][2];   // double-buffered elementwise prefetch

  // ---- prefetch aa (consumed after gram1) ----
#pragma unroll
  for (int mi = 0; mi < 4; ++mi)
#pragma unroll
    for (int nj = 0; nj < 2; ++nj)
      ewA[mi][nj] = *reinterpret_cast<const f32x4*>(
          aa + ewbase + (size_t)(16 * mi) * 8192 + 16 * nj);

  // g=0: link (no elementwise input)
  gram_tile_T(latf + 0 * GSTRIDE, mb_i, mb_j, lane, s);
#pragma unroll
  for (int mi = 0; mi < 4; ++mi)
#pragma unroll
    for (int nj = 0; nj < 2; ++nj)
#pragma unroll
      for (int v = 0; v < 4; ++v)
        o[mi][nj][v] = w0 * sigf(s[mi][nj][v]);

  // ---- prefetch mod (consumed after gram2) ----
#pragma unroll
  for (int mi = 0; mi < 4; ++mi)
#pragma unroll
    for (int nj = 0; nj < 2; ++nj)
      ewB[mi][nj] = *reinterpret_cast<const f32x4*>(
          mod + ewbase + (size_t)(16 * mi) * 8192 + 16 * nj);

  // g=1: aa
  gram_tile_T(latf + 1 * GSTRIDE, mb_i, mb_j, lane, s);
#pragma unroll
  for (int mi = 0; mi < 4; ++mi)
#pragma unroll
    for (int nj = 0; nj < 2; ++nj)
#pragma unroll
      for (int v = 0; v < 4; ++v)
        o[mi][nj][v] += w1 * sigf(s[mi][nj][v] * ewA[mi][nj][v]);

  // ---- prefetch adj into ewA (consumed after gram3) ----
#pragma unroll
  for (int mi = 0; mi < 4; ++mi)
#pragma unroll
    for (int nj = 0; nj < 2; ++nj)
      ewA[mi][nj] = *reinterpret_cast<const f32x4*>(
          adj + ewbase + (size_t)(16 * mi) * 8192 + 16 * nj);

  // g=2: mod
  gram_tile_T(latf + 2 * GSTRIDE, mb_i, mb_j, lane, s);
#pragma unroll
  for (int mi = 0; mi < 4; ++mi)
#pragma unroll
    for (int nj = 0; nj < 2; ++nj)
#pragma unroll
      for (int v = 0; v < 4; ++v)
        o[mi][nj][v] += w2 * sigf(s[mi][nj][v] * ewB[mi][nj][v]);

  // g=3: unlink + combine + store
  gram_tile_T(latf + 3 * GSTRIDE, mb_i, mb_j, lane, s);
#pragma unroll
  for (int mi = 0; mi < 4; ++mi)
#pragma unroll
    for (int nj = 0; nj < 2; ++nj) {
      size_t off = ewbase + (size_t)(16 * mi) * 8192 + 16 * nj;
      f32x4 res;
#pragma unroll
      for (int v = 0; v < 4; ++v) {
        float u = sigf(s[mi][nj][v]);
        res[v] = ewA[mi][nj][v] * (o[mi][nj][v] - u) + u;
      }
      *reinterpret_cast<f32x4*>(out + off) = res;
    }
}

// ------------------------------------------------------------------------------
extern "C" void kernel_launch(void* const* d_in, const int* in_sizes, int n_in,
                              void* d_out, int out_size, void* d_ws, size_t ws_size,
                              hipStream_t stream) {
  const float* feat = (const float*)d_in[0];
  const float* adj  = (const float*)d_in[1];
  const float* aa   = (const float*)d_in[2];
  const float* mod  = (const float*)d_in[3];
  // g order: 0=link, 1=aa, 2=mod, 3=unlink
  const float* W1g[4] = {(const float*)d_in[4], (const float*)d_in[12],
                         (const float*)d_in[16], (const float*)d_in[8]};
  const float* b1g[4] = {(const float*)d_in[5], (const float*)d_in[13],
                         (const float*)d_in[17], (const float*)d_in[9]};
  const float* W2g[4] = {(const float*)d_in[6], (const float*)d_in[14],
                         (const float*)d_in[18], (const float*)d_in[10]};
  const float* b2g[4] = {(const float*)d_in[7], (const float*)d_in[15],
                         (const float*)d_in[19], (const float*)d_in[11]};
  const float* wsv = (const float*)d_in[20];
  float* out = (float*)d_out;

  // workspace layout (elements of ushort)
  unsigned short* featf = (unsigned short*)d_ws;   // 4,194,304 elems (8 MiB)
  unsigned short* hfrag = featf + 4194304;         // 4,194,304
  unsigned short* latf  = hfrag + 4194304;         // 4,194,304
  unsigned short* w1f   = latf + 4194304;          //   262,144
  unsigned short* w2f   = w1f + 262144;            //    65,536
  if (ws_size < 25821184) return;

  k_featfrag<<<2048, 256, 0, stream>>>(feat, featf);
  k_wfrag<<<160, 256, 0, stream>>>(W1g[0], W1g[1], W1g[2], W1g[3],
                                   W2g[0], W2g[1], W2g[2], W2g[3], w1f, w2f);
  k_gemm1<<<dim3(64, 4), 256, 0, stream>>>(featf, w1f, b1g[0], b1g[1], b1g[2], b1g[3], hfrag);
  k_gemm2<<<dim3(64, 4), 256, 0, stream>>>(hfrag, w2f, b2g[0], b2g[1], b2g[2], b2g[3], latf);
  k_ctx<<<8192, 256, 0, stream>>>(latf, adj, aa, mod, wsv, out);
}

// Round 4
// 414.617 us; speedup vs baseline: 2.8900x; 1.0437x over previous
//
#include <hip/hip_runtime.h>

// ---------------------------------------------------------------------------
// meta_model: out = (w0*sig(Ll Ll^T) + w1*sig((La La^T)*aa) + w2*sig((Lm Lm^T)*mod)
//                    - sig(Lu Lu^T)) * adj + sig(Lu Lu^T)
// with L* = mlp(feat), w = softmax(ws)
//
// R3 changes vs R2 (VGPR_Count=84 proved the (256,3)=168-reg cap forced the
// compiler to sink the ew prefetches back to their use sites; in-flight
// bytes/CU ~3.5KB vs 9.2KB needed -> 2.4 TB/s):
//   - ALL 24 elementwise float4 loads (aa, mod, adj = 96 VGPRs) hoisted to
//     kernel top, in consumption order, before gram0
//   - __launch_bounds__(256,2): 256-VGPR cap, total need ~205 -> fits, no
//     sinking; 8 waves/CU with ~24KB in flight each
// ---------------------------------------------------------------------------

typedef __attribute__((ext_vector_type(8))) short short8;
typedef __attribute__((ext_vector_type(4))) float f32x4;

__device__ __forceinline__ unsigned short f2bf(float x) {
  union { float f; unsigned u; } v; v.f = x;
  unsigned u = v.u + 0x7FFFu + ((v.u >> 16) & 1u);   // round-to-nearest-even
  return (unsigned short)(u >> 16);
}

__device__ __forceinline__ float sigf(float x) {
  float e = __builtin_amdgcn_exp2f(-1.4426950408889634f * x);
  return __builtin_amdgcn_rcpf(1.0f + e);
}

// --------------------------- stage A0: feat -> frag -------------------------
__global__ __launch_bounds__(256) void k_featfrag(const float* __restrict__ feat,
                                                  unsigned short* __restrict__ dst) {
  int t = blockIdx.x * 256 + threadIdx.x;   // 8192 rows * 64 chunks
  int row = t >> 6, kc = t & 63;            // 8 cols per thread
  const float4* s = reinterpret_cast<const float4*>(feat + row * 512 + kc * 8);
  float4 v0 = s[0], v1 = s[1];
  short8 o;
  o[0] = f2bf(v0.x); o[1] = f2bf(v0.y); o[2] = f2bf(v0.z); o[3] = f2bf(v0.w);
  o[4] = f2bf(v1.x); o[5] = f2bf(v1.y); o[6] = f2bf(v1.z); o[7] = f2bf(v1.w);
  int mb = row >> 4, kk = kc >> 2;
  int lane = ((kc & 3) << 4) | (row & 15);
  *reinterpret_cast<short8*>(dst + ((size_t)((mb * 16 + kk) * 64 + lane)) * 8) = o;
}

// --------------------- stage A0w: W1/W2 -> B-frag layout ---------------------
__global__ __launch_bounds__(256) void k_wfrag(
    const float* __restrict__ w1_0, const float* __restrict__ w1_1,
    const float* __restrict__ w1_2, const float* __restrict__ w1_3,
    const float* __restrict__ w2_0, const float* __restrict__ w2_1,
    const float* __restrict__ w2_2, const float* __restrict__ w2_3,
    unsigned short* __restrict__ w1f, unsigned short* __restrict__ w2f) {
  int t = blockIdx.x * 256 + threadIdx.x;
  if (t < 32768) {  // W1frag: [g][kk=16][nb=8][lane=64][j=8]
    int lane = t & 63, nb = (t >> 6) & 7, kk = (t >> 9) & 15, g = t >> 13;
    const float* W = g == 0 ? w1_0 : g == 1 ? w1_1 : g == 2 ? w1_2 : w1_3;
    int q = lane >> 4, r = lane & 15;
    int col = nb * 16 + r;
    short8 o;
#pragma unroll
    for (int j = 0; j < 8; ++j) o[j] = f2bf(W[(kk * 32 + q * 8 + j) * 128 + col]);
    *reinterpret_cast<short8*>(w1f + (size_t)t * 8) = o;
  } else if (t < 40960) {  // W2frag: [g][kk=4][nb=8][lane=64][j=8]
    int t2 = t - 32768;
    int lane = t2 & 63, nb = (t2 >> 6) & 7, kk = (t2 >> 9) & 3, g = t2 >> 11;
    const float* W = g == 0 ? w2_0 : g == 1 ? w2_1 : g == 2 ? w2_2 : w2_3;
    int q = lane >> 4, r = lane & 15;
    int col = nb * 16 + r;
    short8 o;
#pragma unroll
    for (int j = 0; j < 8; ++j) o[j] = f2bf(W[(kk * 32 + q * 8 + j) * 128 + col]);
    *reinterpret_cast<short8*>(w2f + (size_t)t2 * 8) = o;
  }
}

// --------------------- stage A1: H = relu(feat@W1cat + b1) -------------------
__global__ __launch_bounds__(256) void k_gemm1(
    const unsigned short* __restrict__ featf, const unsigned short* __restrict__ w1f,
    const float* __restrict__ b1_0, const float* __restrict__ b1_1,
    const float* __restrict__ b1_2, const float* __restrict__ b1_3,
    unsigned short* __restrict__ hfrag) {
  int bi = blockIdx.x, g = blockIdx.y;
  int lane = threadIdx.x & 63, w = threadIdx.x >> 6;
  int wm = w >> 1, wn = w & 1;
  int q = lane >> 4, r = lane & 15;
  int mbase = 8 * bi + 4 * wm;

  f32x4 s[4][4];
#pragma unroll
  for (int mi = 0; mi < 4; ++mi)
#pragma unroll
    for (int nj = 0; nj < 4; ++nj) s[mi][nj] = (f32x4){0.f, 0.f, 0.f, 0.f};

  for (int kk = 0; kk < 16; ++kk) {
    short8 a[4], b[4];
#pragma unroll
    for (int mi = 0; mi < 4; ++mi)
      a[mi] = *reinterpret_cast<const short8*>(
          featf + ((size_t)(((mbase + mi) * 16 + kk) * 64 + lane)) * 8);
#pragma unroll
    for (int nj = 0; nj < 4; ++nj)
      b[nj] = *reinterpret_cast<const short8*>(
          w1f + ((size_t)(((g * 16 + kk) * 8 + 4 * wn + nj) * 64 + lane)) * 8);
#pragma unroll
    for (int mi = 0; mi < 4; ++mi)
#pragma unroll
      for (int nj = 0; nj < 4; ++nj)
        s[mi][nj] = __builtin_amdgcn_mfma_f32_16x16x32_bf16(a[mi], b[nj], s[mi][nj], 0, 0, 0);
  }

  const float* b1 = g == 0 ? b1_0 : g == 1 ? b1_1 : g == 2 ? b1_2 : b1_3;
#pragma unroll
  for (int nj = 0; nj < 4; ++nj) {
    int cl = 64 * wn + 16 * nj + r;
    float bias = b1[cl];
    int Cg = 128 * g + cl;
    int kkd = Cg >> 5;
    int lane2hi = ((Cg >> 3) & 3) << 4;
    int j2 = Cg & 7;
#pragma unroll
    for (int mi = 0; mi < 4; ++mi) {
#pragma unroll
      for (int v = 0; v < 4; ++v) {
        int R = 128 * bi + 64 * wm + 16 * mi + 4 * q + v;
        float val = fmaxf(s[mi][nj][v] + bias, 0.0f);
        int mb = R >> 4;
        int lane2 = lane2hi | (R & 15);
        hfrag[((size_t)((mb * 16 + kkd) * 64 + lane2)) * 8 + j2] = f2bf(val);
      }
    }
  }
}

// --------------------- stage A2: lat_g = H_g@W2_g + b2 -----------------------
__global__ __launch_bounds__(256) void k_gemm2(
    const unsigned short* __restrict__ hfrag, const unsigned short* __restrict__ w2f,
    const float* __restrict__ b2_0, const float* __restrict__ b2_1,
    const float* __restrict__ b2_2, const float* __restrict__ b2_3,
    unsigned short* __restrict__ latf) {
  int bi = blockIdx.x, g = blockIdx.y;
  int lane = threadIdx.x & 63, w = threadIdx.x >> 6;
  int wm = w >> 1, wn = w & 1;
  int q = lane >> 4, r = lane & 15;
  int mbase = 8 * bi + 4 * wm;

  f32x4 s[4][4];
#pragma unroll
  for (int mi = 0; mi < 4; ++mi)
#pragma unroll
    for (int nj = 0; nj < 4; ++nj) s[mi][nj] = (f32x4){0.f, 0.f, 0.f, 0.f};

#pragma unroll
  for (int kk = 0; kk < 4; ++kk) {
    short8 a[4], b[4];
#pragma unroll
    for (int mi = 0; mi < 4; ++mi)
      a[mi] = *reinterpret_cast<const short8*>(
          hfrag + ((size_t)(((mbase + mi) * 16 + 4 * g + kk) * 64 + lane)) * 8);
#pragma unroll
    for (int nj = 0; nj < 4; ++nj)
      b[nj] = *reinterpret_cast<const short8*>(
          w2f + ((size_t)(((g * 4 + kk) * 8 + 4 * wn + nj) * 64 + lane)) * 8);
#pragma unroll
    for (int mi = 0; mi < 4; ++mi)
#pragma unroll
      for (int nj = 0; nj < 4; ++nj)
        s[mi][nj] = __builtin_amdgcn_mfma_f32_16x16x32_bf16(a[mi], b[nj], s[mi][nj], 0, 0, 0);
  }

  const float* b2 = g == 0 ? b2_0 : g == 1 ? b2_1 : g == 2 ? b2_2 : b2_3;
#pragma unroll
  for (int nj = 0; nj < 4; ++nj) {
    int cl = 64 * wn + 16 * nj + r;
    float bias = b2[cl];
    int kkd = cl >> 5;
    int lane2hi = ((cl >> 3) & 3) << 4;
    int j2 = cl & 7;
#pragma unroll
    for (int mi = 0; mi < 4; ++mi) {
#pragma unroll
      for (int v = 0; v < 4; ++v) {
        int R = 128 * bi + 64 * wm + 16 * mi + 4 * q + v;
        float val = s[mi][nj][v] + bias;
        int mb = R >> 4;
        int lane2 = lane2hi | (R & 15);
        latf[((size_t)(((g * 512 + mb) * 4 + kkd) * 64 + lane2)) * 8 + j2] = f2bf(val);
      }
    }
  }
}

// --------------------------- stage B: fused context --------------------------
// Transposed-Gram: s[mi][nj] = sum_k mfma(frag_j, frag_i)  == Lj * Li^T tile.
// Lane l=16q+r, reg v then owns out(row = 16mi + r, col = 16nj + 4q + v).
__device__ __forceinline__ void gram_tile_T(const unsigned short* __restrict__ latg,
                                            int mb_i, int mb_j, int lane,
                                            f32x4 s[4][2]) {
#pragma unroll
  for (int mi = 0; mi < 4; ++mi)
#pragma unroll
    for (int nj = 0; nj < 2; ++nj) s[mi][nj] = (f32x4){0.f, 0.f, 0.f, 0.f};
#pragma unroll
  for (int kk = 0; kk < 4; ++kk) {
    short8 fi[4], fj[2];
#pragma unroll
    for (int mi = 0; mi < 4; ++mi)
      fi[mi] = *reinterpret_cast<const short8*>(
          latg + ((size_t)(((mb_i + mi) * 4 + kk) * 64 + lane)) * 8);
#pragma unroll
    for (int nj = 0; nj < 2; ++nj)
      fj[nj] = *reinterpret_cast<const short8*>(
          latg + ((size_t)(((mb_j + nj) * 4 + kk) * 64 + lane)) * 8);
#pragma unroll
    for (int mi = 0; mi < 4; ++mi)
#pragma unroll
      for (int nj = 0; nj < 2; ++nj)
        s[mi][nj] = __builtin_amdgcn_mfma_f32_16x16x32_bf16(fj[nj], fi[mi], s[mi][nj], 0, 0, 0);
  }
}

__global__ __launch_bounds__(256, 2) void k_ctx(
    const unsigned short* __restrict__ latf,
    const float* __restrict__ adj, const float* __restrict__ aa,
    const float* __restrict__ mod, const float* __restrict__ wsv,
    float* __restrict__ out) {
  // 8192 blocks = 64 (bi, 128-row tiles) x 128 (bj, 64-col tiles).
  // XCD-aware bijective swizzle: each XCD sweeps bj fast with a resident
  // bi-panel -> latf A-panels stay L2-hot.
  int bid = blockIdx.x;
  int swz = (bid & 7) * 1024 + (bid >> 3);
  int bi = swz >> 7;
  int bj = swz & 127;

  int lane = threadIdx.x & 63, w = threadIdx.x >> 6;
  int wm = w >> 1, wn = w & 1;            // 2x2 waves of 64x32
  int q = lane >> 4, r = lane & 15;

  // softmax(ws) — 3 scalars
  float s0 = wsv[0], s1 = wsv[1], s2 = wsv[2];
  float mx = fmaxf(fmaxf(s0, s1), s2);
  float e0 = __builtin_amdgcn_exp2f(1.4426950408889634f * (s0 - mx));
  float e1 = __builtin_amdgcn_exp2f(1.4426950408889634f * (s1 - mx));
  float e2 = __builtin_amdgcn_exp2f(1.4426950408889634f * (s2 - mx));
  float inv = __builtin_amdgcn_rcpf(e0 + e1 + e2);
  float w0 = e0 * inv, w1 = e1 * inv, w2 = e2 * inv;

  int mb_i = 8 * bi + 4 * wm;             // 16-row block base (rows)
  int mb_j = 4 * bj + 2 * wn;             // 16-row block base (cols)

  // elementwise base: row = 128bi + 64wm + r, col = 64bj + 32wn + 4q
  size_t ewbase = (size_t)(128 * bi + 64 * wm + r) * 8192
                + (size_t)(64 * bj + 32 * wn + 4 * q);

  const size_t GSTRIDE = 512u * 4u * 64u * 8u;  // elements per latent in latf

  f32x4 s[4][2], o[4][2];
  f32x4 ewAA[4][2], ewMOD[4][2], ewADJ[4][2];   // 96 VGPRs of prefetch

  // ---- hoist ALL elementwise loads, in consumption order ----
#pragma unroll
  for (int mi = 0; mi < 4; ++mi)
#pragma unroll
    for (int nj = 0; nj < 2; ++nj)
      ewAA[mi][nj] = *reinterpret_cast<const f32x4*>(
          aa + ewbase + (size_t)(16 * mi) * 8192 + 16 * nj);
#pragma unroll
  for (int mi = 0; mi < 4; ++mi)
#pragma unroll
    for (int nj = 0; nj < 2; ++nj)
      ewMOD[mi][nj] = *reinterpret_cast<const f32x4*>(
          mod + ewbase + (size_t)(16 * mi) * 8192 + 16 * nj);
#pragma unroll
  for (int mi = 0; mi < 4; ++mi)
#pragma unroll
    for (int nj = 0; nj < 2; ++nj)
      ewADJ[mi][nj] = *reinterpret_cast<const f32x4*>(
          adj + ewbase + (size_t)(16 * mi) * 8192 + 16 * nj);

  // g=0: link (no elementwise input)
  gram_tile_T(latf + 0 * GSTRIDE, mb_i, mb_j, lane, s);
#pragma unroll
  for (int mi = 0; mi < 4; ++mi)
#pragma unroll
    for (int nj = 0; nj < 2; ++nj)
#pragma unroll
      for (int v = 0; v < 4; ++v)
        o[mi][nj][v] = w0 * sigf(s[mi][nj][v]);

  // g=1: aa
  gram_tile_T(latf + 1 * GSTRIDE, mb_i, mb_j, lane, s);
#pragma unroll
  for (int mi = 0; mi < 4; ++mi)
#pragma unroll
    for (int nj = 0; nj < 2; ++nj)
#pragma unroll
      for (int v = 0; v < 4; ++v)
        o[mi][nj][v] += w1 * sigf(s[mi][nj][v] * ewAA[mi][nj][v]);

  // g=2: mod
  gram_tile_T(latf + 2 * GSTRIDE, mb_i, mb_j, lane, s);
#pragma unroll
  for (int mi = 0; mi < 4; ++mi)
#pragma unroll
    for (int nj = 0; nj < 2; ++nj)
#pragma unroll
      for (int v = 0; v < 4; ++v)
        o[mi][nj][v] += w2 * sigf(s[mi][nj][v] * ewMOD[mi][nj][v]);

  // g=3: unlink + combine + store
  gram_tile_T(latf + 3 * GSTRIDE, mb_i, mb_j, lane, s);
#pragma unroll
  for (int mi = 0; mi < 4; ++mi)
#pragma unroll
    for (int nj = 0; nj < 2; ++nj) {
      size_t off = ewbase + (size_t)(16 * mi) * 8192 + 16 * nj;
      f32x4 res;
#pragma unroll
      for (int v = 0; v < 4; ++v) {
        float u = sigf(s[mi][nj][v]);
        res[v] = ewADJ[mi][nj][v] * (o[mi][nj][v] - u) + u;
      }
      *reinterpret_cast<f32x4*>(out + off) = res;
    }
}

// ------------------------------------------------------------------------------
extern "C" void kernel_launch(void* const* d_in, const int* in_sizes, int n_in,
                              void* d_out, int out_size, void* d_ws, size_t ws_size,
                              hipStream_t stream) {
  const float* feat = (const float*)d_in[0];
  const float* adj  = (const float*)d_in[1];
  const float* aa   = (const float*)d_in[2];
  const float* mod  = (const float*)d_in[3];
  // g order: 0=link, 1=aa, 2=mod, 3=unlink
  const float* W1g[4] = {(const float*)d_in[4], (const float*)d_in[12],
                         (const float*)d_in[16], (const float*)d_in[8]};
  const float* b1g[4] = {(const float*)d_in[5], (const float*)d_in[13],
                         (const float*)d_in[17], (const float*)d_in[9]};
  const float* W2g[4] = {(const float*)d_in[6], (const float*)d_in[14],
                         (const float*)d_in[18], (const float*)d_in[10]};
  const float* b2g[4] = {(const float*)d_in[7], (const float*)d_in[15],
                         (const float*)d_in[19], (const float*)d_in[11]};
  const float* wsv = (const float*)d_in[20];
  float* out = (float*)d_out;

  // workspace layout (elements of ushort)
  unsigned short* featf = (unsigned short*)d_ws;   // 4,194,304 elems (8 MiB)
  unsigned short* hfrag = featf + 4194304;         // 4,194,304
  unsigned short* latf  = hfrag + 4194304;         // 4,194,304
  unsigned short* w1f   = latf + 4194304;          //   262,144
  unsigned short* w2f   = w1f + 262144;            //    65,536
  if (ws_size < 25821184) return;

  k_featfrag<<<2048, 256, 0, stream>>>(feat, featf);
  k_wfrag<<<160, 256, 0, stream>>>(W1g[0], W1g[1], W1g[2], W1g[3],
                                   W2g[0], W2g[1], W2g[2], W2g[3], w1f, w2f);
  k_gemm1<<<dim3(64, 4), 256, 0, stream>>>(featf, w1f, b1g[0], b1g[1], b1g[2], b1g[3], hfrag);
  k_gemm2<<<dim3(64, 4), 256, 0, stream>>>(hfrag, w2f, b2g[0], b2g[1], b2g[2], b2g[3], latf);
  k_ctx<<<8192, 256, 0, stream>>>(latf, adj, aa, mod, wsv, out);
}